// Round 1
// baseline (26591.718 us; speedup 1.0000x reference)
//
#include <hip/hip_runtime.h>
#include <cstdint>
#include <cstddef>

// GRU 3-layer, B=128 T=512 H=512, fp32 in/out.
// Design: persistent kernel, (layer,t) wavefront schedule, 1 grid barrier/step.
// 96 WGs = 3 layers x 32 col-blocks(16 gate-cols). Weights fp16 in LDS (96KB),
// pre-swizzled to MFMA B-fragment order (lane-linear -> no bank conflicts).
// fp16 MFMA (16x16x32) with fp32 accum; hidden state carried fp32 in registers;
// h exchanged cross-layer as fp16, double-buffered by step parity.

#define B_ 128
#define T_ 512
#define H_ 512
#define NWG 96
#define STEPS 514          // 512 + 2 pipeline fill for 3 layers
#define THREADS 128        // 2 waves x 4 m-tiles each (LDS-BW vs MFMA balance)

typedef _Float16 half8_t __attribute__((ext_vector_type(8)));
typedef float f32x4 __attribute__((ext_vector_type(4)));

// ws layout (bytes):
//      0 : barrier   (cnt at int[0], release at int[32])
//    256 : biases    [3][4][512] f32  (r: bih+bhh, z: bih+bhh, ni: bih, nh: bhh)
//  24832 : h16       [3 layers][2 parity][128*512] f16
// 811264 : W16       [96 blocks][49152] f16  (LDS image, fragment-ordered)
#define WS_BIAS 256
#define WS_H16  24832
#define WS_W16  811264

#define MFMA(a, b, c) __builtin_amdgcn_mfma_f32_16x16x32_f16(a, b, c, 0, 0, 0)

__device__ __forceinline__ half8_t ld_h8(const _Float16* __restrict__ p) {
  return *(const half8_t* __restrict__)p;
}
__device__ __forceinline__ half8_t ld_f8(const float* __restrict__ p) {
  const float4 u = *(const float4* __restrict__)p;
  const float4 v = *(const float4* __restrict__)(p + 4);
  half8_t a = { (_Float16)u.x, (_Float16)u.y, (_Float16)u.z, (_Float16)u.w,
                (_Float16)v.x, (_Float16)v.y, (_Float16)v.z, (_Float16)v.w };
  return a;
}

__global__ void zero_ws(int* __restrict__ ws) {
  int i = blockIdx.x * 256 + threadIdx.x;
  if (i < 202816) ws[i] = 0;   // zeroes barrier + bias region + h16 buffers
}

__global__ void pack_b(const float* __restrict__ bi0, const float* __restrict__ bh0,
                       const float* __restrict__ bi1, const float* __restrict__ bh1,
                       const float* __restrict__ bi2, const float* __restrict__ bh2,
                       float* __restrict__ biases) {
  int idx = blockIdx.x * 256 + threadIdx.x;
  if (idx >= 1536) return;
  int l = idx >> 9, j = idx & 511;
  const float* bi = l == 0 ? bi0 : (l == 1 ? bi1 : bi2);
  const float* bh = l == 0 ? bh0 : (l == 1 ? bh1 : bh2);
  biases[(l*4+0)*512 + j] = bi[j] + bh[j];               // r: fused
  biases[(l*4+1)*512 + j] = bi[512+j] + bh[512+j];       // z: fused
  biases[(l*4+2)*512 + j] = bi[1024+j];                  // i_n bias
  biases[(l*4+3)*512 + j] = bh[1024+j];                  // h_n bias (scaled by r later)
}

// W16[bx][e]: e = (kb*3 + gate)*512 + lane*8 + el ; col=lane&15, q=lane>>4
// maps to W[gate*512 + g*16+col][k], k = kb*32 + q*8 + el; k<512 -> W_ih else W_hh.
__global__ void pack_w(const float* __restrict__ Wih0, const float* __restrict__ Whh0,
                       const float* __restrict__ Wih1, const float* __restrict__ Whh1,
                       const float* __restrict__ Wih2, const float* __restrict__ Whh2,
                       _Float16* __restrict__ W16) {
  const int e = blockIdx.x * 256 + threadIdx.x;   // 0..49151
  const int bxw = blockIdx.y;                     // l*32 + g
  const int l = bxw >> 5, g = bxw & 31;
  const int kb = e / 1536;
  const int rem = e - kb * 1536;
  const int gate = rem >> 9;
  const int r2 = rem & 511;
  const int lane = r2 >> 3;
  const int el = r2 & 7;
  const int col = lane & 15, q = lane >> 4;
  const int k = kb * 32 + q * 8 + el;             // 0..1023
  const int row = gate * 512 + g * 16 + col;
  const float* Wih = l == 0 ? Wih0 : (l == 1 ? Wih1 : Wih2);
  const float* Whh = l == 0 ? Whh0 : (l == 1 ? Whh1 : Whh2);
  const float v = (k < 512) ? Wih[row * 512 + k] : Whh[row * 512 + (k - 512)];
  W16[(size_t)bxw * 49152 + e] = (_Float16)v;
}

__global__ void __launch_bounds__(THREADS, 1)
gru_main(const float* __restrict__ x, float* __restrict__ out,
         int* __restrict__ bar, const float* __restrict__ biases,
         _Float16* __restrict__ h16, const _Float16* __restrict__ W16) {
  extern __shared__ _Float16 Wlds[];    // 49152 f16 = 96 KB
  const int tid = threadIdx.x;
  const int lane = tid & 63;
  const int wave = tid >> 6;
  const int bx = blockIdx.x;
  const int layer = bx >> 5;
  const int g = bx & 31;

  { // stage weights once; linear copy (image already fragment-ordered)
    const int* __restrict__ s4 = (const int*)(W16 + (size_t)bx * 49152);
    int* d4 = (int*)Wlds;
    for (int i = tid; i < 24576; i += THREADS) d4[i] = s4[i];
  }
  __syncthreads();

  const int col = lane & 15;            // A-row (m) and B/C col (n) lane index
  const int q = lane >> 4;
  const int koff = q << 3;
  const int j = (g << 4) + col;
  const float b_r  = biases[(layer*4+0)*512 + j];
  const float b_z  = biases[(layer*4+1)*512 + j];
  const float b_ni = biases[(layer*4+2)*512 + j];
  const float b_nh = biases[(layer*4+3)*512 + j];

  const int mtb = wave * 4;             // 4 m-tiles per wave
  int rows[4];
  #pragma unroll
  for (int m = 0; m < 4; ++m) rows[m] = (mtb + m) * 16 + col;

  float hprev[4][4];                    // fp32 hidden carry, this WG's 16 cols
  #pragma unroll
  for (int m = 0; m < 4; ++m)
    #pragma unroll
    for (int i = 0; i < 4; ++i) hprev[m][i] = 0.f;

  const _Float16* __restrict__ WlB = Wlds + lane * 8;

  for (int s = 0; s < STEPS; ++s) {
    const int t = s - layer;            // wavefront schedule
    if ((unsigned)t < (unsigned)T_) {
      const f32x4 zero4 = {0.f, 0.f, 0.f, 0.f};
      f32x4 aR[4], aZ[4], aNI[4], aNH[4];
      #pragma unroll
      for (int m = 0; m < 4; ++m) { aR[m]=zero4; aZ[m]=zero4; aNI[m]=zero4; aNH[m]=zero4; }

      const int par = (s - 1) & 1;      // read buffers produced at step s-1
      const _Float16* __restrict__ hown = h16 + ((layer * 2 + par) << 16) + koff;

      // ---- first K-half: input side (x for layer0, h_{l-1} for layers 1,2) ----
      if (layer == 0) {
        const float* __restrict__ xb = x + (size_t)t * H_ + koff;
        #pragma unroll 2
        for (int kb = 0; kb < 16; ++kb) {
          half8_t a[4];
          #pragma unroll
          for (int m = 0; m < 4; ++m)
            a[m] = ld_f8(xb + (size_t)rows[m] * (T_ * H_) + kb * 32);
          const _Float16* wb = WlB + kb * 1536;
          const half8_t br = ld_h8(wb);
          const half8_t bz = ld_h8(wb + 512);
          const half8_t bn = ld_h8(wb + 1024);
          #pragma unroll
          for (int m = 0; m < 4; ++m) {
            aR[m]  = MFMA(a[m], br, aR[m]);
            aZ[m]  = MFMA(a[m], bz, aZ[m]);
            aNI[m] = MFMA(a[m], bn, aNI[m]);
          }
        }
      } else {
        const _Float16* __restrict__ hin = h16 + (((layer - 1) * 2 + par) << 16) + koff;
        #pragma unroll 2
        for (int kb = 0; kb < 16; ++kb) {
          half8_t a[4];
          #pragma unroll
          for (int m = 0; m < 4; ++m)
            a[m] = ld_h8(hin + rows[m] * H_ + kb * 32);
          const _Float16* wb = WlB + kb * 1536;
          const half8_t br = ld_h8(wb);
          const half8_t bz = ld_h8(wb + 512);
          const half8_t bn = ld_h8(wb + 1024);
          #pragma unroll
          for (int m = 0; m < 4; ++m) {
            aR[m]  = MFMA(a[m], br, aR[m]);
            aZ[m]  = MFMA(a[m], bz, aZ[m]);
            aNI[m] = MFMA(a[m], bn, aNI[m]);
          }
        }
      }
      // ---- second K-half: own h_{l,t-1} (r,z keep accumulating; n -> separate acc) ----
      #pragma unroll 2
      for (int kb = 16; kb < 32; ++kb) {
        half8_t a[4];
        #pragma unroll
        for (int m = 0; m < 4; ++m)
          a[m] = ld_h8(hown + rows[m] * H_ + (kb - 16) * 32);
        const _Float16* wb = WlB + kb * 1536;
        const half8_t br = ld_h8(wb);
        const half8_t bz = ld_h8(wb + 512);
        const half8_t bn = ld_h8(wb + 1024);
        #pragma unroll
        for (int m = 0; m < 4; ++m) {
          aR[m]  = MFMA(a[m], br, aR[m]);
          aZ[m]  = MFMA(a[m], bz, aZ[m]);
          aNH[m] = MFMA(a[m], bn, aNH[m]);
        }
      }

      // ---- epilogue: gates in fp32, write h16 (+ masked output for layer 2) ----
      _Float16* __restrict__ hw = h16 + ((layer * 2 + (s & 1)) << 16);
      #pragma unroll
      for (int m = 0; m < 4; ++m) {
        #pragma unroll
        for (int i = 0; i < 4; ++i) {
          const int brow = (mtb + m) * 16 + q * 4 + i;   // C/D: row = q*4 + reg
          const float rr = aR[m][i] + b_r;
          const float zz = aZ[m][i] + b_z;
          const float r = 1.f / (1.f + __expf(-rr));
          const float z = 1.f / (1.f + __expf(-zz));
          const float pre = (aNI[m][i] + b_ni) + r * (aNH[m][i] + b_nh);
          const float e2 = __expf(-2.f * fabsf(pre));    // overflow-safe tanh
          float nt = (1.f - e2) / (1.f + e2);
          nt = (pre < 0.f) ? -nt : nt;
          float hn = (1.f - z) * nt + z * hprev[m][i];
          if (layer == 2) {
            const size_t oidx = ((size_t)brow * T_ + t) * H_ + j;
            const float xv = x[oidx];                    // exact fp32 mask source
            hn = (xv != 0.f) ? hn : 0.f;                 // masked h2 is carried
            out[oidx] = hn;
          }
          hprev[m][i] = hn;
          hw[brow * H_ + j] = (_Float16)hn;
        }
      }
    }

    // ---- grid barrier (counting, agent-scope release/acquire) ----
    __syncthreads();
    if (tid == 0) {
      const int old = __hip_atomic_fetch_add(bar, 1, __ATOMIC_ACQ_REL, __HIP_MEMORY_SCOPE_AGENT);
      if (old == (s + 1) * NWG - 1) {
        __hip_atomic_store(bar + 32, s + 1, __ATOMIC_RELEASE, __HIP_MEMORY_SCOPE_AGENT);
      } else {
        while (__hip_atomic_load(bar + 32, __ATOMIC_ACQUIRE, __HIP_MEMORY_SCOPE_AGENT) < s + 1)
          __builtin_amdgcn_s_sleep(8);
      }
    }
    __syncthreads();
  }
}

extern "C" void kernel_launch(void* const* d_in, const int* in_sizes, int n_in,
                              void* d_out, int out_size, void* d_ws, size_t ws_size,
                              hipStream_t stream) {
  (void)in_sizes; (void)n_in; (void)out_size; (void)ws_size;
  const float* x    = (const float*)d_in[0];
  const float* Wih0 = (const float*)d_in[1];
  const float* Whh0 = (const float*)d_in[2];
  const float* bih0 = (const float*)d_in[3];
  const float* bhh0 = (const float*)d_in[4];
  const float* Wih1 = (const float*)d_in[5];
  const float* Whh1 = (const float*)d_in[6];
  const float* bih1 = (const float*)d_in[7];
  const float* bhh1 = (const float*)d_in[8];
  const float* Wih2 = (const float*)d_in[9];
  const float* Whh2 = (const float*)d_in[10];
  const float* bih2 = (const float*)d_in[11];
  const float* bhh2 = (const float*)d_in[12];

  char* ws = (char*)d_ws;
  int* bar = (int*)ws;
  float* biases = (float*)(ws + WS_BIAS);
  _Float16* h16 = (_Float16*)(ws + WS_H16);
  _Float16* W16 = (_Float16*)(ws + WS_W16);

  // 96 KB dynamic LDS (> 64 KB default cap)
  hipFuncSetAttribute((const void*)gru_main, hipFuncAttributeMaxDynamicSharedMemorySize, 98304);

  zero_ws<<<dim3(793), dim3(256), 0, stream>>>((int*)ws);
  pack_b<<<dim3(6), dim3(256), 0, stream>>>(bih0, bhh0, bih1, bhh1, bih2, bhh2, biases);
  pack_w<<<dim3(192, 96), dim3(256), 0, stream>>>(Wih0, Whh0, Wih1, Whh1, Wih2, Whh2, W16);
  gru_main<<<dim3(NWG), dim3(THREADS), 98304, stream>>>(x, (float*)d_out, bar, biases, h16, W16);
}

// Round 2
// 13847.586 us; speedup vs baseline: 1.9203x; 1.9203x over previous
//
#include <hip/hip_runtime.h>
#include <cstdint>
#include <cstddef>

// GRU 3-layer, B=128 T=512 H=512, fp32 in/out.
// Persistent kernel, (layer,t) wavefront schedule, 1 grid barrier/step.
// 96 WGs = 3 layers x 32 col-blocks(16 gate-cols). Weights fp16 in LDS (96KB),
// fragment-ordered. fp16 MFMA, fp32 hidden carry in registers, h exchanged as
// fp16 double-buffered in ws.
// R2: distributed-flag barrier (no contended RMW, no per-poll invalidates),
//     256 threads (4 waves x 2 m-tiles), unroll 4 for MLP.

#define B_ 128
#define T_ 512
#define H_ 512
#define NWG 96
#define STEPS 514
#define THREADS 256

typedef _Float16 half8_t __attribute__((ext_vector_type(8)));
typedef float f32x4 __attribute__((ext_vector_type(4)));

// ws layout (bytes):
//       0 : release word (int)
//     128 : flags[96], stride 128 B
//   16384 : biases [3][4][512] f32
//   40960 : h16 [3][2][128*512] f16
//  827392 : W16 [96][49152] f16 (LDS image, fragment-ordered)
#define WS_BIAS 16384
#define WS_H16  40960
#define WS_W16  827392

#define MFMA(a, b, c) __builtin_amdgcn_mfma_f32_16x16x32_f16(a, b, c, 0, 0, 0)

__device__ __forceinline__ half8_t ld_h8(const _Float16* __restrict__ p) {
  return *(const half8_t* __restrict__)p;
}
__device__ __forceinline__ half8_t ld_f8(const float* __restrict__ p) {
  const float4 u = *(const float4* __restrict__)p;
  const float4 v = *(const float4* __restrict__)(p + 4);
  half8_t a = { (_Float16)u.x, (_Float16)u.y, (_Float16)u.z, (_Float16)u.w,
                (_Float16)v.x, (_Float16)v.y, (_Float16)v.z, (_Float16)v.w };
  return a;
}

__global__ void zero_ws(int* __restrict__ ws) {
  int i = blockIdx.x * 256 + threadIdx.x;
  if (i < 206848) ws[i] = 0;   // release + flags + biases + h16
}

__global__ void pack_b(const float* __restrict__ bi0, const float* __restrict__ bh0,
                       const float* __restrict__ bi1, const float* __restrict__ bh1,
                       const float* __restrict__ bi2, const float* __restrict__ bh2,
                       float* __restrict__ biases) {
  int idx = blockIdx.x * 256 + threadIdx.x;
  if (idx >= 1536) return;
  int l = idx >> 9, j = idx & 511;
  const float* bi = l == 0 ? bi0 : (l == 1 ? bi1 : bi2);
  const float* bh = l == 0 ? bh0 : (l == 1 ? bh1 : bh2);
  biases[(l*4+0)*512 + j] = bi[j] + bh[j];
  biases[(l*4+1)*512 + j] = bi[512+j] + bh[512+j];
  biases[(l*4+2)*512 + j] = bi[1024+j];
  biases[(l*4+3)*512 + j] = bh[1024+j];
}

// W16[bx][e]: e = (kb*3 + gate)*512 + lane*8 + el ; col=lane&15, q=lane>>4
// -> W[gate*512 + g*16+col][k], k = kb*32 + q*8 + el; k<512 -> W_ih else W_hh.
__global__ void pack_w(const float* __restrict__ Wih0, const float* __restrict__ Whh0,
                       const float* __restrict__ Wih1, const float* __restrict__ Whh1,
                       const float* __restrict__ Wih2, const float* __restrict__ Whh2,
                       _Float16* __restrict__ W16) {
  const int e = blockIdx.x * 256 + threadIdx.x;
  const int bxw = blockIdx.y;
  const int l = bxw >> 5, g = bxw & 31;
  const int kb = e / 1536;
  const int rem = e - kb * 1536;
  const int gate = rem >> 9;
  const int r2 = rem & 511;
  const int lane = r2 >> 3;
  const int el = r2 & 7;
  const int col = lane & 15, q = lane >> 4;
  const int k = kb * 32 + q * 8 + el;
  const int row = gate * 512 + g * 16 + col;
  const float* Wih = l == 0 ? Wih0 : (l == 1 ? Wih1 : Wih2);
  const float* Whh = l == 0 ? Whh0 : (l == 1 ? Whh1 : Whh2);
  const float v = (k < 512) ? Wih[row * 512 + k] : Whh[row * 512 + (k - 512)];
  W16[(size_t)bxw * 49152 + e] = (_Float16)v;
}

__global__ void __launch_bounds__(THREADS, 1)
gru_main(const float* __restrict__ x, float* __restrict__ out,
         int* __restrict__ bar, const float* __restrict__ biases,
         _Float16* __restrict__ h16, const _Float16* __restrict__ W16) {
  extern __shared__ _Float16 Wlds[];    // 49152 f16 = 96 KB
  const int tid = threadIdx.x;
  const int lane = tid & 63;
  const int wave = tid >> 6;
  const int bx = blockIdx.x;
  const int layer = bx >> 5;
  const int g = bx & 31;

  int* __restrict__ rel = bar;          // release word
  int* __restrict__ flags = bar + 32;   // flag i at +i*32 ints (128 B apart)

  { // stage weights once; linear copy (image already fragment-ordered)
    const int* __restrict__ s4 = (const int*)(W16 + (size_t)bx * 49152);
    int* d4 = (int*)Wlds;
    for (int i = tid; i < 24576; i += THREADS) d4[i] = s4[i];
  }
  __syncthreads();

  const int col = lane & 15;
  const int q = lane >> 4;
  const int koff = q << 3;
  const int j = (g << 4) + col;
  const float b_r  = biases[(layer*4+0)*512 + j];
  const float b_z  = biases[(layer*4+1)*512 + j];
  const float b_ni = biases[(layer*4+2)*512 + j];
  const float b_nh = biases[(layer*4+3)*512 + j];

  const int mtb = wave * 2;             // 2 m-tiles per wave (4 waves)
  int rows[2];
  #pragma unroll
  for (int m = 0; m < 2; ++m) rows[m] = (mtb + m) * 16 + col;

  float hprev[2][4];
  #pragma unroll
  for (int m = 0; m < 2; ++m)
    #pragma unroll
    for (int i = 0; i < 4; ++i) hprev[m][i] = 0.f;

  const _Float16* __restrict__ WlB = Wlds + lane * 8;

  for (int s = 0; s < STEPS; ++s) {
    const int t = s - layer;
    if ((unsigned)t < (unsigned)T_) {
      const f32x4 zero4 = {0.f, 0.f, 0.f, 0.f};
      f32x4 aR[2], aZ[2], aNI[2], aNH[2];
      #pragma unroll
      for (int m = 0; m < 2; ++m) { aR[m]=zero4; aZ[m]=zero4; aNI[m]=zero4; aNH[m]=zero4; }

      const int par = (s - 1) & 1;
      const _Float16* __restrict__ hown = h16 + ((layer * 2 + par) << 16) + koff;

      // ---- first K-half: x (layer 0) or h_{l-1} (layers 1,2) ----
      if (layer == 0) {
        const float* __restrict__ xb = x + (size_t)t * H_ + koff;
        #pragma unroll 4
        for (int kb = 0; kb < 16; ++kb) {
          half8_t a[2];
          #pragma unroll
          for (int m = 0; m < 2; ++m)
            a[m] = ld_f8(xb + (size_t)rows[m] * (T_ * H_) + kb * 32);
          const _Float16* wb = WlB + kb * 1536;
          const half8_t br = ld_h8(wb);
          const half8_t bz = ld_h8(wb + 512);
          const half8_t bn = ld_h8(wb + 1024);
          #pragma unroll
          for (int m = 0; m < 2; ++m) {
            aR[m]  = MFMA(a[m], br, aR[m]);
            aZ[m]  = MFMA(a[m], bz, aZ[m]);
            aNI[m] = MFMA(a[m], bn, aNI[m]);
          }
        }
      } else {
        const _Float16* __restrict__ hin = h16 + (((layer - 1) * 2 + par) << 16) + koff;
        #pragma unroll 4
        for (int kb = 0; kb < 16; ++kb) {
          half8_t a[2];
          #pragma unroll
          for (int m = 0; m < 2; ++m)
            a[m] = ld_h8(hin + rows[m] * H_ + kb * 32);
          const _Float16* wb = WlB + kb * 1536;
          const half8_t br = ld_h8(wb);
          const half8_t bz = ld_h8(wb + 512);
          const half8_t bn = ld_h8(wb + 1024);
          #pragma unroll
          for (int m = 0; m < 2; ++m) {
            aR[m]  = MFMA(a[m], br, aR[m]);
            aZ[m]  = MFMA(a[m], bz, aZ[m]);
            aNI[m] = MFMA(a[m], bn, aNI[m]);
          }
        }
      }
      // ---- second K-half: own h_{l,t-1} ----
      #pragma unroll 4
      for (int kb = 16; kb < 32; ++kb) {
        half8_t a[2];
        #pragma unroll
        for (int m = 0; m < 2; ++m)
          a[m] = ld_h8(hown + rows[m] * H_ + (kb - 16) * 32);
        const _Float16* wb = WlB + kb * 1536;
        const half8_t br = ld_h8(wb);
        const half8_t bz = ld_h8(wb + 512);
        const half8_t bn = ld_h8(wb + 1024);
        #pragma unroll
        for (int m = 0; m < 2; ++m) {
          aR[m]  = MFMA(a[m], br, aR[m]);
          aZ[m]  = MFMA(a[m], bz, aZ[m]);
          aNH[m] = MFMA(a[m], bn, aNH[m]);
        }
      }

      // ---- epilogue ----
      _Float16* __restrict__ hw = h16 + ((layer * 2 + (s & 1)) << 16);
      #pragma unroll
      for (int m = 0; m < 2; ++m) {
        #pragma unroll
        for (int i = 0; i < 4; ++i) {
          const int brow = (mtb + m) * 16 + q * 4 + i;   // C/D: row = q*4 + reg
          const float rr = aR[m][i] + b_r;
          const float zz = aZ[m][i] + b_z;
          const float r = 1.f / (1.f + __expf(-rr));
          const float z = 1.f / (1.f + __expf(-zz));
          const float pre = (aNI[m][i] + b_ni) + r * (aNH[m][i] + b_nh);
          const float e2 = __expf(-2.f * fabsf(pre));
          float nt = (1.f - e2) / (1.f + e2);
          nt = (pre < 0.f) ? -nt : nt;
          float hn = (1.f - z) * nt + z * hprev[m][i];
          if (layer == 2) {
            const size_t oidx = ((size_t)brow * T_ + t) * H_ + j;
            const float xv = x[oidx];                    // exact fp32 mask source
            hn = (xv != 0.f) ? hn : 0.f;
            out[oidx] = hn;
          }
          hprev[m][i] = hn;
          hw[brow * H_ + j] = (_Float16)hn;
        }
      }
    }

    // ---- distributed-flag grid barrier ----
    __syncthreads();
    if (tid == 0)   // one RELEASE per WG: flushes this XCD's dirty h16 to LLC
      __hip_atomic_store(flags + bx * 32, s + 1, __ATOMIC_RELEASE, __HIP_MEMORY_SCOPE_AGENT);
    if (bx == 0 && tid < NWG) {   // master sweeps all flags, relaxed (no inv)
      while (__hip_atomic_load(flags + tid * 32, __ATOMIC_RELAXED, __HIP_MEMORY_SCOPE_AGENT) < s + 1)
        __builtin_amdgcn_s_sleep(2);
    }
    __syncthreads();
    if (bx == 0 && tid == 0)
      __hip_atomic_store(rel, s + 1, __ATOMIC_RELEASE, __HIP_MEMORY_SCOPE_AGENT);
    if (tid == 0) {
      while (__hip_atomic_load(rel, __ATOMIC_RELAXED, __HIP_MEMORY_SCOPE_AGENT) < s + 1)
        __builtin_amdgcn_s_sleep(2);
      (void)__hip_atomic_load(rel, __ATOMIC_ACQUIRE, __HIP_MEMORY_SCOPE_AGENT);  // one inv/step
    }
    __syncthreads();
  }
}

extern "C" void kernel_launch(void* const* d_in, const int* in_sizes, int n_in,
                              void* d_out, int out_size, void* d_ws, size_t ws_size,
                              hipStream_t stream) {
  (void)in_sizes; (void)n_in; (void)out_size; (void)ws_size;
  const float* x    = (const float*)d_in[0];
  const float* Wih0 = (const float*)d_in[1];
  const float* Whh0 = (const float*)d_in[2];
  const float* bih0 = (const float*)d_in[3];
  const float* bhh0 = (const float*)d_in[4];
  const float* Wih1 = (const float*)d_in[5];
  const float* Whh1 = (const float*)d_in[6];
  const float* bih1 = (const float*)d_in[7];
  const float* bhh1 = (const float*)d_in[8];
  const float* Wih2 = (const float*)d_in[9];
  const float* Whh2 = (const float*)d_in[10];
  const float* bih2 = (const float*)d_in[11];
  const float* bhh2 = (const float*)d_in[12];

  char* ws = (char*)d_ws;
  int* bar = (int*)ws;
  float* biases = (float*)(ws + WS_BIAS);
  _Float16* h16 = (_Float16*)(ws + WS_H16);
  _Float16* W16 = (_Float16*)(ws + WS_W16);

  hipFuncSetAttribute((const void*)gru_main, hipFuncAttributeMaxDynamicSharedMemorySize, 98304);

  zero_ws<<<dim3(808), dim3(256), 0, stream>>>((int*)ws);
  pack_b<<<dim3(6), dim3(256), 0, stream>>>(bih0, bhh0, bih1, bhh1, bih2, bhh2, biases);
  pack_w<<<dim3(192, 96), dim3(256), 0, stream>>>(Wih0, Whh0, Wih1, Whh1, Wih2, Whh2, W16);
  gru_main<<<dim3(NWG), dim3(THREADS), 98304, stream>>>(x, (float*)d_out, bar, biases, h16, W16);
}